// Round 6
// baseline (611.259 us; speedup 1.0000x reference)
//
#include <hip/hip_runtime.h>
#include <stdint.h>

#define BB 1024
#define SS 512
#define HH 128
#define MM 4            // batch rows per block
#define BLK 512
#define NBLK (BB / MM)  // 256 blocks -> 1 per CU
#define HPS 136         // hpack row stride in f16 (272B rows, 16B-aligned)

typedef float f32x4 __attribute__((ext_vector_type(4)));
typedef _Float16 f16x8 __attribute__((ext_vector_type(8)));

#define LO_SCALE 2048.0f
#define LO_INV   (1.0f / 2048.0f)
#define LO_INV2  (LO_INV * LO_INV)

__device__ __forceinline__ float sigf(float x) { return 1.0f / (1.0f + __expf(-x)); }
__device__ __forceinline__ float tanh_fast(float x) { return 2.0f / (1.0f + __expf(-2.0f * x)) - 1.0f; }

__global__ __launch_bounds__(BLK, 2) void pig_kernel(
    const float* __restrict__ x0, const float* __restrict__ v_seq,
    const float* __restrict__ W_ih, const float* __restrict__ W_hh,
    const float* __restrict__ b_ih, const float* __restrict__ b_hh,
    const float* __restrict__ W_out, const float* __restrict__ b_out,
    const float* __restrict__ W_r1, const float* __restrict__ b_r1,
    const float* __restrict__ W_r2, const float* __restrict__ b_r2,
    float* __restrict__ out)
{
    // hpack row r = 4m+p: p=0 -> h_hi[m], p=1 -> h_lo[m]*2048, p=2,3 -> zero
    __shared__ __align__(16) _Float16 hpack[2][16 * HPS];
    __shared__ __align__(16) float    part_x[2][64];   // [buf][wave*8 + m*2 + o]
    __shared__ float xprev[MM * 2];
    __shared__ float vring[3][MM * 2];

    const int tid  = threadIdx.x;
    const int wave = tid >> 6;
    const int lane = tid & 63;
    const int quad = lane >> 4;
    const int col  = lane & 15;
    const int row0 = blockIdx.x * MM;
    const int j    = wave * 16 + col;   // this lane's hidden index

    // ---- W_hh B-fragments: wave w owns gates nt*128 + w*16 .. +15 ----
    f16x8 whi[3][4], wlo[3][4];
#pragma unroll
    for (int nt = 0; nt < 3; ++nt) {
        const int g = nt * HH + j;
#pragma unroll
        for (int kk = 0; kk < 4; ++kk) {
            const float* p = W_hh + g * HH + kk * 32 + quad * 8;
            f16x8 fh, fl;
#pragma unroll
            for (int i = 0; i < 8; ++i) {
                float w = p[i];
                _Float16 h = (_Float16)w;
                fh[i] = h;
                fl[i] = (_Float16)((w - (float)h) * LO_SCALE);
            }
            whi[nt][kk] = fh;
            wlo[nt][kk] = fl;
        }
    }

    // ---- gate-math per-lane constants (hidden index j, batch row m=quad) ----
    const float wr0 = W_ih[j*2],        wr1 = W_ih[j*2+1];
    const float wz0 = W_ih[(HH+j)*2],   wz1 = W_ih[(HH+j)*2+1];
    const float wn0 = W_ih[(2*HH+j)*2], wn1 = W_ih[(2*HH+j)*2+1];
    const float br  = b_ih[j]      + b_hh[j];
    const float bz  = b_ih[HH+j]   + b_hh[HH+j];
    const float bni = b_ih[2*HH+j];
    const float bnh = b_hh[2*HH+j];

    // ---- output-head partial constants (all waves) ----
    const float woj0 = W_out[j];        // o=0
    const float woj1 = W_out[HH + j];   // o=1

    // ---- wave1 epilogue constants ----
    const int m1 = lane >> 4;
    const int kb = (lane & 15) * 4;
    float a[4][4], ab_[4], w2a[4], w2b[4];
#pragma unroll
    for (int u = 0; u < 4; ++u) {
#pragma unroll
        for (int q = 0; q < 4; ++q) a[u][q] = W_r1[(kb+u)*4 + q];
        ab_[u] = b_r1[kb+u];
        w2a[u] = W_r2[kb+u];        // o=0
        w2b[u] = W_r2[64 + kb+u];   // o=1
    }
    const float bo_l = b_out[lane & 1];
    const float b2_l = b_r2[lane & 1];

    // ---- init ----
    for (int idx = tid; idx < 2 * 16 * HPS; idx += BLK) ((_Float16*)hpack)[idx] = (_Float16)0.0f;
    if (tid < MM*2) {
        xprev[tid]    = x0[(size_t)(row0 + (tid >> 1)) * 2 + (tid & 1)];
        vring[0][tid] = v_seq[((size_t)(row0 + (tid >> 1)) * SS) * 2 + (tid & 1)];
    }
    __syncthreads();

    float hold = 0.0f;   // h[quad][j] in fp32 — the trajectory-critical state
    for (int t = 0; t <= SS; ++t) {
        const int cur = t & 1, nxt = cur ^ 1;

        float vpre = 0.0f;   // wave0 prefetches v(t+1)
        if (wave == 0 && lane < MM*2 && (t + 1) < SS)
            vpre = v_seq[((size_t)(row0 + (lane >> 1)) * SS + (t + 1)) * 2 + (lane & 1)];

        if (t < SS) {
            f32x4 aH0 = {0,0,0,0}, aH1 = {0,0,0,0}, aH2 = {0,0,0,0};
            f32x4 aL0 = {0,0,0,0}, aL1 = {0,0,0,0}, aL2 = {0,0,0,0};
#pragma unroll
            for (int kk = 0; kk < 4; ++kk) {
                f16x8 af = *(const f16x8*)&hpack[cur][col * HPS + kk * 32 + quad * 8];
                aH0 = __builtin_amdgcn_mfma_f32_16x16x32_f16(af, whi[0][kk], aH0, 0, 0, 0);
                aH1 = __builtin_amdgcn_mfma_f32_16x16x32_f16(af, whi[1][kk], aH1, 0, 0, 0);
                aH2 = __builtin_amdgcn_mfma_f32_16x16x32_f16(af, whi[2][kk], aH2, 0, 0, 0);
                aL0 = __builtin_amdgcn_mfma_f32_16x16x32_f16(af, wlo[0][kk], aL0, 0, 0, 0);
                aL1 = __builtin_amdgcn_mfma_f32_16x16x32_f16(af, wlo[1][kk], aL1, 0, 0, 0);
                aL2 = __builtin_amdgcn_mfma_f32_16x16x32_f16(af, wlo[2][kk], aL2, 0, 0, 0);
            }
            // lane (quad,col): acc[0] = hi-row, acc[1] = lo-row for batch m=quad
            const float gh0 = aH0[0] + (aH0[1] + aL0[0]) * LO_INV + aL0[1] * LO_INV2;
            const float gh1 = aH1[0] + (aH1[1] + aL1[0]) * LO_INV + aL1[1] * LO_INV2;
            const float gh2 = aH2[0] + (aH2[1] + aL2[0]) * LO_INV + aL2[1] * LO_INV2;

            const float* vb = vring[t % 3];
            const float v0 = vb[quad*2], v1 = vb[quad*2+1];
            const float r = sigf(gh0 + v0*wr0 + v1*wr1 + br);
            const float z = sigf(gh1 + v0*wz0 + v1*wz1 + bz);
            const float n = tanh_fast(v0*wn0 + v1*wn1 + bni + r * (gh2 + bnh));
            hold = n + z * (hold - n);

            _Float16 hh = (_Float16)hold;
            hpack[nxt][(4*quad)     * HPS + j] = hh;
            hpack[nxt][(4*quad + 1) * HPS + j] = (_Float16)((hold - (float)hh) * LO_SCALE);

            // ---- distributed output-head partials (fp32 h, in-register) ----
            float px0 = hold * woj0;
            float px1 = hold * woj1;
#pragma unroll
            for (int s = 8; s >= 1; s >>= 1) {
                px0 += __shfl_xor(px0, s, 64);
                px1 += __shfl_xor(px1, s, 64);
            }
            if (col == 0) {
                part_x[cur][wave*8 + quad*2]     = px0;
                part_x[cur][wave*8 + quad*2 + 1] = px1;
            }
        }

        if (wave == 1 && t > 0) {   // compact epilogue for step tt = t-1
            const int tt = t - 1;
            float val = part_x[nxt][lane];          // lane = w*8 + (m*2+o)
            val += __shfl_xor(val, 8, 64);
            val += __shfl_xor(val, 16, 64);
            val += __shfl_xor(val, 32, 64);
            const float xpred = val + bo_l;          // valid on lanes 0..7 (m*2+o)

            // residual MLP fully in registers (all 64 lanes; m=m1, units kb..kb+3)
            const float xp0 = xprev[m1*2], xp1 = xprev[m1*2+1];
            const float* vtt = vring[tt % 3];
            const float v0 = vtt[m1*2], v1 = vtt[m1*2+1];
            float rss0 = 0.0f, rss1 = 0.0f;
#pragma unroll
            for (int u = 0; u < 4; ++u) {
                const float hu = fmaxf(ab_[u] + a[u][0]*xp0 + a[u][1]*xp1 + a[u][2]*v0 + a[u][3]*v1, 0.0f);
                rss0 += hu * w2a[u];
                rss1 += hu * w2b[u];
            }
#pragma unroll
            for (int s = 8; s >= 1; s >>= 1) {
                rss0 += __shfl_xor(rss0, s, 64);
                rss1 += __shfl_xor(rss1, s, 64);
            }
            const float r0 = __shfl(rss0, (lane >> 1) << 4, 64);
            const float r1 = __shfl(rss1, (lane >> 1) << 4, 64);
            if (lane < 8) {                          // lane = m*2 + o
                const float resid = ((lane & 1) ? r1 : r0) + b2_l;
                const float xpv   = xprev[lane];
                const float vv    = vtt[lane];
                const float viol  = xpred - (xpv + vv + resid);
                const size_t base = ((size_t)(row0 + (lane >> 1)) * SS + tt) * 2 + (lane & 1);
                out[base] = xpred;
                out[(size_t)BB * SS * 2 + base] = viol;
                xprev[lane] = xpred;                 // after all reads of old xprev (wave-ordered)
            }
        }

        if (wave == 0 && lane < MM*2 && (t + 1) < SS)
            vring[(t + 1) % 3][lane] = vpre;

        __syncthreads();   // the single per-step barrier
    }
}

extern "C" void kernel_launch(void* const* d_in, const int* in_sizes, int n_in,
                              void* d_out, int out_size, void* d_ws, size_t ws_size,
                              hipStream_t stream) {
    pig_kernel<<<dim3(NBLK), dim3(BLK), 0, stream>>>(
        (const float*)d_in[0],  (const float*)d_in[1],  (const float*)d_in[2],
        (const float*)d_in[3],  (const float*)d_in[4],  (const float*)d_in[5],
        (const float*)d_in[6],  (const float*)d_in[7],  (const float*)d_in[8],
        (const float*)d_in[9],  (const float*)d_in[10], (const float*)d_in[11],
        (float*)d_out);
}

// Round 7
// 572.282 us; speedup vs baseline: 1.0681x; 1.0681x over previous
//
#include <hip/hip_runtime.h>
#include <stdint.h>

#define BB 1024
#define SS 512
#define HH 128
#define MM 4            // batch rows per block
#define BLK 512
#define NBLK (BB / MM)  // 256 blocks -> 1 per CU
#define HPS 136         // hpack row stride in f16 (272B rows, 16B-aligned)

typedef float f32x4 __attribute__((ext_vector_type(4)));
typedef float f32x2 __attribute__((ext_vector_type(2)));
typedef _Float16 f16x8 __attribute__((ext_vector_type(8)));

#define LO_SCALE 2048.0f
#define LO_INV   (1.0f / 2048.0f)
#define LO_INV2  (LO_INV * LO_INV)

__device__ __forceinline__ float sigf(float x) { return 1.0f / (1.0f + __expf(-x)); }
__device__ __forceinline__ float tanh_fast(float x) { return 2.0f / (1.0f + __expf(-2.0f * x)) - 1.0f; }

__global__ __launch_bounds__(BLK, 2) void pig_kernel(
    const float* __restrict__ x0, const float* __restrict__ v_seq,
    const float* __restrict__ W_ih, const float* __restrict__ W_hh,
    const float* __restrict__ b_ih, const float* __restrict__ b_hh,
    const float* __restrict__ W_out, const float* __restrict__ b_out,
    const float* __restrict__ W_r1, const float* __restrict__ b_r1,
    const float* __restrict__ W_r2, const float* __restrict__ b_r2,
    float* __restrict__ out)
{
    // hpack row r = 4m+p: p=0 -> h_hi[m], p=1 -> h_lo[m]*2048, p=2,3 -> zero
    __shared__ __align__(16) _Float16 hpack[2][16 * HPS];
    __shared__ __align__(16) float    v_lds[SS * 8];       // [t][m*2+o], 16 KB
    __shared__ __align__(16) float    xb[2][MM][128];      // [plane][m][(tt&63)*2+o], 4 KB
    __shared__ __align__(16) float    part_x[2][64];       // [buf][wave*8 + m*2 + o]
    __shared__ float xprev[MM * 2];                        // wave1-only after init

    const int tid  = threadIdx.x;
    const int wave = tid >> 6;
    const int lane = tid & 63;
    const int quad = lane >> 4;
    const int col  = lane & 15;
    const int row0 = blockIdx.x * MM;
    const int j    = wave * 16 + col;   // this lane's hidden index

    // ---- W_hh B-fragments: wave w owns gates nt*128 + w*16 .. +15 ----
    f16x8 whi[3][4], wlo[3][4];
#pragma unroll
    for (int nt = 0; nt < 3; ++nt) {
        const int g = nt * HH + j;
#pragma unroll
        for (int kk = 0; kk < 4; ++kk) {
            const float* p = W_hh + g * HH + kk * 32 + quad * 8;
            f16x8 fh, fl;
#pragma unroll
            for (int i = 0; i < 8; ++i) {
                float w = p[i];
                _Float16 h = (_Float16)w;
                fh[i] = h;
                fl[i] = (_Float16)((w - (float)h) * LO_SCALE);
            }
            whi[nt][kk] = fh;
            wlo[nt][kk] = fl;
        }
    }

    // ---- gate-math per-lane constants (hidden index j, batch row m=quad) ----
    const float wr0 = W_ih[j*2],        wr1 = W_ih[j*2+1];
    const float wz0 = W_ih[(HH+j)*2],   wz1 = W_ih[(HH+j)*2+1];
    const float wn0 = W_ih[(2*HH+j)*2], wn1 = W_ih[(2*HH+j)*2+1];
    const float br  = b_ih[j]      + b_hh[j];
    const float bz  = b_ih[HH+j]   + b_hh[HH+j];
    const float bni = b_ih[2*HH+j];
    const float bnh = b_hh[2*HH+j];

    // ---- output-head partial constants (all waves) ----
    const float woj0 = W_out[j];        // o=0
    const float woj1 = W_out[HH + j];   // o=1

    // ---- wave1 epilogue constants ----
    const int m1 = lane >> 4;
    const int kb = (lane & 15) * 4;
    float a[4][4], ab_[4], w2a[4], w2b[4];
#pragma unroll
    for (int u = 0; u < 4; ++u) {
#pragma unroll
        for (int q = 0; q < 4; ++q) a[u][q] = W_r1[(kb+u)*4 + q];
        ab_[u] = b_r1[kb+u];
        w2a[u] = W_r2[kb+u];        // o=0
        w2b[u] = W_r2[64 + kb+u];   // o=1
    }
    const float bo_l = b_out[lane & 1];
    const float b2_l = b_r2[lane & 1];

    // ---- init: zero hpack, bulk-load v_seq slice into LDS, xprev = x0 ----
    for (int idx = tid; idx < 2 * 16 * HPS; idx += BLK) ((_Float16*)hpack)[idx] = (_Float16)0.0f;
    for (int idx = tid; idx < MM * SS * 2; idx += BLK) {
        const int m = idx >> 10, i = idx & 1023;          // i = t*2 + o
        v_lds[(i >> 1) * 8 + m * 2 + (i & 1)] = v_seq[(size_t)(row0 + m) * (SS * 2) + i];
    }
    if (tid < MM*2)
        xprev[tid] = x0[(size_t)(row0 + (tid >> 1)) * 2 + (tid & 1)];
    __syncthreads();

    float hold = 0.0f;   // h[quad][j] in fp32 — the trajectory-critical state
    for (int t = 0; t <= SS; ++t) {
        const int cur = t & 1, nxt = cur ^ 1;

        if (t < SS) {
            f32x4 aH0 = {0,0,0,0}, aH1 = {0,0,0,0}, aH2 = {0,0,0,0};
            f32x4 aL0 = {0,0,0,0}, aL1 = {0,0,0,0}, aL2 = {0,0,0,0};
#pragma unroll
            for (int kk = 0; kk < 4; ++kk) {
                f16x8 af = *(const f16x8*)&hpack[cur][col * HPS + kk * 32 + quad * 8];
                aH0 = __builtin_amdgcn_mfma_f32_16x16x32_f16(af, whi[0][kk], aH0, 0, 0, 0);
                aH1 = __builtin_amdgcn_mfma_f32_16x16x32_f16(af, whi[1][kk], aH1, 0, 0, 0);
                aH2 = __builtin_amdgcn_mfma_f32_16x16x32_f16(af, whi[2][kk], aH2, 0, 0, 0);
                aL0 = __builtin_amdgcn_mfma_f32_16x16x32_f16(af, wlo[0][kk], aL0, 0, 0, 0);
                aL1 = __builtin_amdgcn_mfma_f32_16x16x32_f16(af, wlo[1][kk], aL1, 0, 0, 0);
                aL2 = __builtin_amdgcn_mfma_f32_16x16x32_f16(af, wlo[2][kk], aL2, 0, 0, 0);
            }
            // lane (quad,col): acc[0] = hi-row, acc[1] = lo-row for batch m=quad
            const float gh0 = aH0[0] + (aH0[1] + aL0[0]) * LO_INV + aL0[1] * LO_INV2;
            const float gh1 = aH1[0] + (aH1[1] + aL1[0]) * LO_INV + aL1[1] * LO_INV2;
            const float gh2 = aH2[0] + (aH2[1] + aL2[0]) * LO_INV + aL2[1] * LO_INV2;

            const f32x2 vv2 = *(const f32x2*)&v_lds[t * 8 + quad * 2];
            const float v0 = vv2[0], v1 = vv2[1];
            const float r = sigf(gh0 + v0*wr0 + v1*wr1 + br);
            const float z = sigf(gh1 + v0*wz0 + v1*wz1 + bz);
            const float n = tanh_fast(v0*wn0 + v1*wn1 + bni + r * (gh2 + bnh));
            hold = n + z * (hold - n);

            _Float16 hh = (_Float16)hold;
            hpack[nxt][(4*quad)     * HPS + j] = hh;
            hpack[nxt][(4*quad + 1) * HPS + j] = (_Float16)((hold - (float)hh) * LO_SCALE);

            // distributed output-head partials (fp32 h, in-register)
            float px0 = hold * woj0;
            float px1 = hold * woj1;
#pragma unroll
            for (int s = 8; s >= 1; s >>= 1) {
                px0 += __shfl_xor(px0, s, 64);
                px1 += __shfl_xor(px1, s, 64);
            }
            if (col == 0) {
                part_x[cur][wave*8 + quad*2]     = px0;
                part_x[cur][wave*8 + quad*2 + 1] = px1;
            }
        }

        if (wave == 1 && t > 0) {   // epilogue for step tt = t-1 (all LDS, no global)
            const int tt = t - 1;
            float val = part_x[nxt][lane];          // lane = w*8 + (m*2+o)
            val += __shfl_xor(val, 8, 64);
            val += __shfl_xor(val, 16, 64);
            val += __shfl_xor(val, 32, 64);
            const float xpred = val + bo_l;          // valid on lanes 0..7

            // residual MLP fully in registers (m = m1, units kb..kb+3)
            const float xp0 = xprev[m1*2], xp1 = xprev[m1*2+1];
            const f32x2 vt2 = *(const f32x2*)&v_lds[tt * 8 + m1 * 2];
            float rss0 = 0.0f, rss1 = 0.0f;
#pragma unroll
            for (int u = 0; u < 4; ++u) {
                const float hu = fmaxf(ab_[u] + a[u][0]*xp0 + a[u][1]*xp1 + a[u][2]*vt2[0] + a[u][3]*vt2[1], 0.0f);
                rss0 += hu * w2a[u];
                rss1 += hu * w2b[u];
            }
#pragma unroll
            for (int s = 8; s >= 1; s >>= 1) {
                rss0 += __shfl_xor(rss0, s, 64);
                rss1 += __shfl_xor(rss1, s, 64);
            }
            const float r0 = __shfl(rss0, (lane >> 1) << 4, 64);
            const float r1 = __shfl(rss1, (lane >> 1) << 4, 64);
            const int slot = tt & 63;
            if (lane < 8) {                          // lane = m*2 + o
                const float resid = ((lane & 1) ? r1 : r0) + b2_l;
                const float xpv   = xprev[lane];
                const float vv    = v_lds[tt * 8 + lane];
                const float viol  = xpred - (xpv + vv + resid);
                xb[0][lane >> 1][slot*2 + (lane & 1)] = xpred;
                xb[1][lane >> 1][slot*2 + (lane & 1)] = viol;
                xprev[lane] = xpred;
            }
            if (slot == 63) {                        // bulk flush: 64 steps x 8 outputs x 2 planes
                const int t0 = tt - 63;
                const int mF = lane >> 4, cF = lane & 15;
                const size_t gbase = (size_t)(row0 + mF) * (SS * 2) + t0 * 2 + cF * 8;
                const f32x4 x0v = *(const f32x4*)&xb[0][mF][cF*8];
                const f32x4 x1v = *(const f32x4*)&xb[0][mF][cF*8 + 4];
                const f32x4 b0v = *(const f32x4*)&xb[1][mF][cF*8];
                const f32x4 b1v = *(const f32x4*)&xb[1][mF][cF*8 + 4];
                *(f32x4*)&out[gbase]     = x0v;
                *(f32x4*)&out[gbase + 4] = x1v;
                *(f32x4*)&out[(size_t)BB * SS * 2 + gbase]     = b0v;
                *(f32x4*)&out[(size_t)BB * SS * 2 + gbase + 4] = b1v;
            }
        }

        __syncthreads();   // single per-step barrier; no outstanding vmem except after flushes
    }
}

extern "C" void kernel_launch(void* const* d_in, const int* in_sizes, int n_in,
                              void* d_out, int out_size, void* d_ws, size_t ws_size,
                              hipStream_t stream) {
    pig_kernel<<<dim3(NBLK), dim3(BLK), 0, stream>>>(
        (const float*)d_in[0],  (const float*)d_in[1],  (const float*)d_in[2],
        (const float*)d_in[3],  (const float*)d_in[4],  (const float*)d_in[5],
        (const float*)d_in[6],  (const float*)d_in[7],  (const float*)d_in[8],
        (const float*)d_in[9],  (const float*)d_in[10], (const float*)d_in[11],
        (float*)d_out);
}

// Round 8
// 490.217 us; speedup vs baseline: 1.2469x; 1.1674x over previous
//
#include <hip/hip_runtime.h>
#include <stdint.h>

#define BB 1024
#define SS 512
#define HH 128
#define MM 4            // batch rows per block
#define BLK 512
#define NBLK (BB / MM)  // 256 blocks -> 1 per CU
#define HPS 136         // hpack row stride in f16
#define RS 32           // h-trajectory ring slots (flush every 32 steps)

typedef float f32x4 __attribute__((ext_vector_type(4)));
typedef float f32x2 __attribute__((ext_vector_type(2)));
typedef _Float16 f16x8 __attribute__((ext_vector_type(8)));

#define LO_SCALE 2048.0f
#define LO_INV   (1.0f / 2048.0f)
#define LO_INV2  (LO_INV * LO_INV)

__device__ __forceinline__ float sigf(float x) { return 1.0f / (1.0f + __expf(-x)); }
__device__ __forceinline__ float tanh_fast(float x) { return 2.0f / (1.0f + __expf(-2.0f * x)) - 1.0f; }

__global__ __launch_bounds__(BLK, 2) void pig_kernel(
    const float* __restrict__ x0, const float* __restrict__ v_seq,
    const float* __restrict__ W_ih, const float* __restrict__ W_hh,
    const float* __restrict__ b_ih, const float* __restrict__ b_hh,
    const float* __restrict__ W_out, const float* __restrict__ b_out,
    const float* __restrict__ W_r1, const float* __restrict__ b_r1,
    const float* __restrict__ W_r2, const float* __restrict__ b_r2,
    float* __restrict__ out)
{
    // hpack row r = 4m+p: p=0 -> h_hi[m], p=1 -> h_lo[m]*2048, p=2,3 -> zero
    __shared__ __align__(16) _Float16 hpack[2][16 * HPS];   // 8.7 KB
    __shared__ __align__(16) _Float16 ring[RS * 4 * 128];   // 32 KB: [slot][m][j]
    __shared__ __align__(16) float    v_lds[SS * 8];        // 16 KB: [t][m*2+o]
    __shared__ __align__(16) float    xs[RS + 1][8];        // x_pred window (+carry at [0])
    __shared__ __align__(16) float    wpk[64][8];           // {W_r1[u][0..3], b_r1[u], W_r2[0][u], W_r2[1][u], 0}
    __shared__ float xc[2][8];                              // x_prev carry, flush-parity buffered

    const int tid  = threadIdx.x;
    const int wave = tid >> 6;
    const int lane = tid & 63;
    const int quad = lane >> 4;
    const int col  = lane & 15;
    const int row0 = blockIdx.x * MM;
    const int j    = wave * 16 + col;   // this lane's hidden index

    // ---- W_hh B-fragments: wave w owns gates nt*128 + w*16 .. +15 ----
    f16x8 whi[3][4], wlo[3][4];
#pragma unroll
    for (int nt = 0; nt < 3; ++nt) {
        const int g = nt * HH + j;
#pragma unroll
        for (int kk = 0; kk < 4; ++kk) {
            const float* p = W_hh + g * HH + kk * 32 + quad * 8;
            f16x8 fh, fl;
#pragma unroll
            for (int i = 0; i < 8; ++i) {
                float w = p[i];
                _Float16 h = (_Float16)w;
                fh[i] = h;
                fl[i] = (_Float16)((w - (float)h) * LO_SCALE);
            }
            whi[nt][kk] = fh;
            wlo[nt][kk] = fl;
        }
    }

    // ---- gate-math per-lane constants (hidden index j, batch row m=quad) ----
    const float wr0 = W_ih[j*2],        wr1 = W_ih[j*2+1];
    const float wz0 = W_ih[(HH+j)*2],   wz1 = W_ih[(HH+j)*2+1];
    const float wn0 = W_ih[(2*HH+j)*2], wn1 = W_ih[(2*HH+j)*2+1];
    const float br  = b_ih[j]      + b_hh[j];
    const float bz  = b_ih[HH+j]   + b_hh[HH+j];
    const float bni = b_ih[2*HH+j];
    const float bnh = b_hh[2*HH+j];

    // ---- pass-A constants: group g8 = tid>>3 -> (o, m, tt8); lane-in-group l8 ----
    const int g8  = tid >> 3;
    const int l8  = tid & 7;
    const int oA  = g8 & 1;
    const int mA  = (g8 >> 1) & 3;
    const int tt8 = g8 >> 3;            // 0..7
    float woA[16];
#pragma unroll
    for (int i = 0; i < 16; ++i) woA[i] = W_out[oA * HH + l8 * 16 + i];
    const float boA = b_out[oA];

    // ---- pass-B constants: (tt, m, quarter) ----
    const int qB = tid & 3;
    const int mB = (tid >> 2) & 3;
    const int tB = tid >> 4;            // 0..31
    const float b2B = b_r2[qB & 1];

    // ---- init ----
    for (int idx = tid; idx < 2 * 16 * HPS; idx += BLK) ((_Float16*)hpack)[idx] = (_Float16)0.0f;
    for (int idx = tid; idx < MM * SS * 2; idx += BLK) {
        const int m = idx >> 10, i = idx & 1023;          // i = t*2 + o
        v_lds[(i >> 1) * 8 + m * 2 + (i & 1)] = v_seq[(size_t)(row0 + m) * (SS * 2) + i];
    }
    if (tid < 64) {   // packed residual-MLP weights
        wpk[tid][0] = W_r1[tid*4];   wpk[tid][1] = W_r1[tid*4+1];
        wpk[tid][2] = W_r1[tid*4+2]; wpk[tid][3] = W_r1[tid*4+3];
        wpk[tid][4] = b_r1[tid];
        wpk[tid][5] = W_r2[tid];     wpk[tid][6] = W_r2[64 + tid];
        wpk[tid][7] = 0.0f;
    }
    if (tid < 8)
        xc[0][tid] = x0[(size_t)(row0 + (tid >> 1)) * 2 + (tid & 1)];
    __syncthreads();

    float hold = 0.0f;   // h[quad][j] in fp32 — the only recurrent state
    for (int t = 0; t < SS; ++t) {
        const int cur = t & 1, nxt = cur ^ 1;

        // ---------- the bare recurrence ----------
        f32x4 aH0 = {0,0,0,0}, aH1 = {0,0,0,0}, aH2 = {0,0,0,0};
        f32x4 aL0 = {0,0,0,0}, aL1 = {0,0,0,0}, aL2 = {0,0,0,0};
#pragma unroll
        for (int kk = 0; kk < 4; ++kk) {
            f16x8 af = *(const f16x8*)&hpack[cur][col * HPS + kk * 32 + quad * 8];
            aH0 = __builtin_amdgcn_mfma_f32_16x16x32_f16(af, whi[0][kk], aH0, 0, 0, 0);
            aH1 = __builtin_amdgcn_mfma_f32_16x16x32_f16(af, whi[1][kk], aH1, 0, 0, 0);
            aH2 = __builtin_amdgcn_mfma_f32_16x16x32_f16(af, whi[2][kk], aH2, 0, 0, 0);
            aL0 = __builtin_amdgcn_mfma_f32_16x16x32_f16(af, wlo[0][kk], aL0, 0, 0, 0);
            aL1 = __builtin_amdgcn_mfma_f32_16x16x32_f16(af, wlo[1][kk], aL1, 0, 0, 0);
            aL2 = __builtin_amdgcn_mfma_f32_16x16x32_f16(af, wlo[2][kk], aL2, 0, 0, 0);
        }
        const float gh0 = aH0[0] + (aH0[1] + aL0[0]) * LO_INV + aL0[1] * LO_INV2;
        const float gh1 = aH1[0] + (aH1[1] + aL1[0]) * LO_INV + aL1[1] * LO_INV2;
        const float gh2 = aH2[0] + (aH2[1] + aL2[0]) * LO_INV + aL2[1] * LO_INV2;

        const f32x2 vv2 = *(const f32x2*)&v_lds[t * 8 + quad * 2];
        const float r = sigf(gh0 + vv2[0]*wr0 + vv2[1]*wr1 + br);
        const float z = sigf(gh1 + vv2[0]*wz0 + vv2[1]*wz1 + bz);
        const float n = tanh_fast(vv2[0]*wn0 + vv2[1]*wn1 + bni + r * (gh2 + bnh));
        hold = n + z * (hold - n);

        const _Float16 hh = (_Float16)hold;
        hpack[nxt][(4*quad)     * HPS + j] = hh;
        hpack[nxt][(4*quad + 1) * HPS + j] = (_Float16)((hold - (float)hh) * LO_SCALE);
        ring[((t & (RS-1)) * 4 + quad) * 128 + j] = hh;   // h_seq[t] for the epilogue

        __syncthreads();

        // ---------- batched epilogue every RS steps ----------
        if ((t & (RS - 1)) == (RS - 1)) {
            const int f  = t >> 5;       // flush index
            const int t0 = t - (RS - 1);

            // pass A: x_pred for the window (8-lane dot groups, 4 passes)
            if (tid < 8) xs[0][tid] = xc[f & 1][tid];
#pragma unroll
            for (int p = 0; p < 4; ++p) {
                const int tt = p * 8 + tt8;
                const f16x8 h0 = *(const f16x8*)&ring[(tt * 4 + mA) * 128 + l8 * 16];
                const f16x8 h1 = *(const f16x8*)&ring[(tt * 4 + mA) * 128 + l8 * 16 + 8];
                float acc = 0.0f;
#pragma unroll
                for (int i = 0; i < 8; ++i) {
                    acc += (float)h0[i] * woA[i];
                    acc += (float)h1[i] * woA[8 + i];
                }
                acc += __shfl_xor(acc, 1, 64);
                acc += __shfl_xor(acc, 2, 64);
                acc += __shfl_xor(acc, 4, 64);
                if (l8 == 0) xs[1 + tt][mA * 2 + oA] = acc + boA;
            }
            __syncthreads();

            // pass B: residual MLP + violations + stores; thread = (tB, mB, qB)
            {
                const float xp0 = xs[tB][mB*2], xp1 = xs[tB][mB*2+1];
                const f32x2 vt2 = *(const f32x2*)&v_lds[(t0 + tB) * 8 + mB * 2];
                float rss0 = 0.0f, rss1 = 0.0f;
#pragma unroll
                for (int uu = 0; uu < 16; ++uu) {
                    const int u = qB * 16 + uu;
                    const f32x4 wA = *(const f32x4*)&wpk[u][0];
                    const f32x4 wB = *(const f32x4*)&wpk[u][4];
                    const float hu = fmaxf(wB[0] + wA[0]*xp0 + wA[1]*xp1 + wA[2]*vt2[0] + wA[3]*vt2[1], 0.0f);
                    rss0 += hu * wB[1];
                    rss1 += hu * wB[2];
                }
                rss0 += __shfl_xor(rss0, 1, 64);
                rss1 += __shfl_xor(rss1, 1, 64);
                rss0 += __shfl_xor(rss0, 2, 64);
                rss1 += __shfl_xor(rss1, 2, 64);
                if (qB < 2) {
                    const int o = qB;
                    const float xpred = xs[tB + 1][mB*2 + o];
                    const float xpv   = xs[tB][mB*2 + o];
                    const float vv    = v_lds[(t0 + tB) * 8 + mB*2 + o];
                    const float resid = (o ? rss1 : rss0) + b2B;
                    const float viol  = xpred - (xpv + vv + resid);
                    const size_t base = (size_t)(row0 + mB) * (SS * 2) + (t0 + tB) * 2 + o;
                    out[base] = xpred;
                    out[(size_t)BB * SS * 2 + base] = viol;
                }
                if (tid < 8) xc[(f + 1) & 1][tid] = xs[RS][tid];   // carry to next window
            }
            __syncthreads();
        }
    }
}

extern "C" void kernel_launch(void* const* d_in, const int* in_sizes, int n_in,
                              void* d_out, int out_size, void* d_ws, size_t ws_size,
                              hipStream_t stream) {
    pig_kernel<<<dim3(NBLK), dim3(BLK), 0, stream>>>(
        (const float*)d_in[0],  (const float*)d_in[1],  (const float*)d_in[2],
        (const float*)d_in[3],  (const float*)d_in[4],  (const float*)d_in[5],
        (const float*)d_in[6],  (const float*)d_in[7],  (const float*)d_in[8],
        (const float*)d_in[9],  (const float*)d_in[10], (const float*)d_in[11],
        (float*)d_out);
}

// Round 9
// 394.915 us; speedup vs baseline: 1.5478x; 1.2413x over previous
//
#include <hip/hip_runtime.h>
#include <stdint.h>

#define BB 1024
#define SS 512
#define HH 128
#define MM 4            // batch rows per block
#define BLK 512
#define NBLK (BB / MM)  // 256 blocks -> 1 per CU
#define HPS 136         // hpack row stride in f16 (272B rows: 16B-aligned, quads split banks)
#define RS 32           // h-trajectory ring slots (flush every 32 steps)
#define RStr 144        // ring row stride in f16 (288B: quad*8-bank offset -> 2-way max = free)

typedef float f32x4 __attribute__((ext_vector_type(4)));
typedef float f32x2 __attribute__((ext_vector_type(2)));
typedef _Float16 f16x8 __attribute__((ext_vector_type(8)));

#define LO_SCALE 2048.0f
#define LO_INV   (1.0f / 2048.0f)

__device__ __forceinline__ float sigf(float x) { return 1.0f / (1.0f + __expf(-x)); }
__device__ __forceinline__ float tanh_fast(float x) { return 2.0f / (1.0f + __expf(-2.0f * x)) - 1.0f; }

__global__ __launch_bounds__(BLK, 2) void pig_kernel(
    const float* __restrict__ x0, const float* __restrict__ v_seq,
    const float* __restrict__ W_ih, const float* __restrict__ W_hh,
    const float* __restrict__ b_ih, const float* __restrict__ b_hh,
    const float* __restrict__ W_out, const float* __restrict__ b_out,
    const float* __restrict__ W_r1, const float* __restrict__ b_r1,
    const float* __restrict__ W_r2, const float* __restrict__ b_r2,
    float* __restrict__ out)
{
    // hpack row r = 4m+p: p=0 -> h_hi[m], p=1 -> h_lo[m]*2048, p=2,3 -> zero
    __shared__ __align__(16) _Float16 hpack[2][16 * HPS];   // 8.7 KB
    __shared__ __align__(16) _Float16 ring[RS * 4 * RStr];  // 36 KB: [slot][m][j]
    __shared__ __align__(16) float    v_lds[SS * 8];        // 16 KB: [t][m*2+o]
    __shared__ __align__(16) float    xs[RS + 1][8];        // x_pred window (+carry at [0])
    __shared__ __align__(16) float    wpk[64][8];           // {W_r1[u][0..3], b_r1[u], W_r2[0][u], W_r2[1][u], 0}
    __shared__ float xc[2][8];                              // x_prev carry, flush-parity buffered

    const int tid  = threadIdx.x;
    const int wave = tid >> 6;
    const int lane = tid & 63;
    const int quad = lane >> 4;
    const int col  = lane & 15;
    const int row0 = blockIdx.x * MM;
    const int j    = wave * 16 + col;   // this lane's hidden index

    // ---- W_hh B-fragments (f16 only): wave w owns gates nt*128 + w*16 .. +15 ----
    // 12 frags = 48 VGPRs: stays in VGPRs, no AGPR round-trip
    f16x8 whi[3][4];
#pragma unroll
    for (int nt = 0; nt < 3; ++nt) {
        const int g = nt * HH + j;
#pragma unroll
        for (int kk = 0; kk < 4; ++kk) {
            const float* p = W_hh + g * HH + kk * 32 + quad * 8;
            f16x8 fh;
#pragma unroll
            for (int i = 0; i < 8; ++i) fh[i] = (_Float16)p[i];
            whi[nt][kk] = fh;
        }
    }

    // ---- gate-math per-lane constants (hidden index j, batch row m=quad) ----
    const float wr0 = W_ih[j*2],        wr1 = W_ih[j*2+1];
    const float wz0 = W_ih[(HH+j)*2],   wz1 = W_ih[(HH+j)*2+1];
    const float wn0 = W_ih[(2*HH+j)*2], wn1 = W_ih[(2*HH+j)*2+1];
    const float br  = b_ih[j]      + b_hh[j];
    const float bz  = b_ih[HH+j]   + b_hh[HH+j];
    const float bni = b_ih[2*HH+j];
    const float bnh = b_hh[2*HH+j];

    // ---- pass-A constants: group g8 = tid>>3 -> (o, m, tt8); lane-in-group l8 ----
    const int g8  = tid >> 3;
    const int l8  = tid & 7;
    const int oA  = g8 & 1;
    const int mA  = (g8 >> 1) & 3;
    const int tt8 = g8 >> 3;            // 0..7
    float woA[16];
#pragma unroll
    for (int i = 0; i < 16; ++i) woA[i] = W_out[oA * HH + l8 * 16 + i];
    const float boA = b_out[oA];

    // ---- pass-B constants: (tt, m, quarter) ----
    const int qB = tid & 3;
    const int mB = (tid >> 2) & 3;
    const int tB = tid >> 4;            // 0..31
    const float b2B = b_r2[qB & 1];

    // ---- init ----
    for (int idx = tid; idx < 2 * 16 * HPS; idx += BLK) ((_Float16*)hpack)[idx] = (_Float16)0.0f;
    for (int idx = tid; idx < MM * SS * 2; idx += BLK) {
        const int m = idx >> 10, i = idx & 1023;          // i = t*2 + o
        v_lds[(i >> 1) * 8 + m * 2 + (i & 1)] = v_seq[(size_t)(row0 + m) * (SS * 2) + i];
    }
    if (tid < 64) {   // packed residual-MLP weights
        wpk[tid][0] = W_r1[tid*4];   wpk[tid][1] = W_r1[tid*4+1];
        wpk[tid][2] = W_r1[tid*4+2]; wpk[tid][3] = W_r1[tid*4+3];
        wpk[tid][4] = b_r1[tid];
        wpk[tid][5] = W_r2[tid];     wpk[tid][6] = W_r2[64 + tid];
        wpk[tid][7] = 0.0f;
    }
    if (tid < 8)
        xc[0][tid] = x0[(size_t)(row0 + (tid >> 1)) * 2 + (tid & 1)];
    __syncthreads();

    float hold = 0.0f;   // h[quad][j] in fp32 — the only recurrent state
    for (int t = 0; t < SS; ++t) {
        const int cur = t & 1, nxt = cur ^ 1;

        // ---------- the bare recurrence: 12 MFMA ----------
        f32x4 aH0 = {0,0,0,0}, aH1 = {0,0,0,0}, aH2 = {0,0,0,0};
#pragma unroll
        for (int kk = 0; kk < 4; ++kk) {
            f16x8 af = *(const f16x8*)&hpack[cur][col * HPS + kk * 32 + quad * 8];
            aH0 = __builtin_amdgcn_mfma_f32_16x16x32_f16(af, whi[0][kk], aH0, 0, 0, 0);
            aH1 = __builtin_amdgcn_mfma_f32_16x16x32_f16(af, whi[1][kk], aH1, 0, 0, 0);
            aH2 = __builtin_amdgcn_mfma_f32_16x16x32_f16(af, whi[2][kk], aH2, 0, 0, 0);
        }
        // acc[0] = h_hi . W ; acc[1] = (h_lo*2048) . W  -> exact-h gh
        const float gh0 = aH0[0] + aH0[1] * LO_INV;
        const float gh1 = aH1[0] + aH1[1] * LO_INV;
        const float gh2 = aH2[0] + aH2[1] * LO_INV;

        const f32x2 vv2 = *(const f32x2*)&v_lds[t * 8 + quad * 2];
        const float r = sigf(gh0 + vv2[0]*wr0 + vv2[1]*wr1 + br);
        const float z = sigf(gh1 + vv2[0]*wz0 + vv2[1]*wz1 + bz);
        const float n = tanh_fast(vv2[0]*wn0 + vv2[1]*wn1 + bni + r * (gh2 + bnh));
        hold = n + z * (hold - n);

        const _Float16 hh = (_Float16)hold;
        hpack[nxt][(4*quad)     * HPS + j] = hh;
        hpack[nxt][(4*quad + 1) * HPS + j] = (_Float16)((hold - (float)hh) * LO_SCALE);
        ring[((t & (RS-1)) * 4 + quad) * RStr + j] = hh;   // h_seq[t] for the epilogue

        __syncthreads();

        // ---------- batched epilogue every RS steps ----------
        if ((t & (RS - 1)) == (RS - 1)) {
            const int f  = t >> 5;       // flush index
            const int t0 = t - (RS - 1);

            // pass A: x_pred for the window (8-lane dot groups, 4 passes)
            if (tid < 8) xs[0][tid] = xc[f & 1][tid];
#pragma unroll
            for (int p = 0; p < 4; ++p) {
                const int tt = p * 8 + tt8;
                const f16x8 h0 = *(const f16x8*)&ring[(tt * 4 + mA) * RStr + l8 * 16];
                const f16x8 h1 = *(const f16x8*)&ring[(tt * 4 + mA) * RStr + l8 * 16 + 8];
                float acc = 0.0f;
#pragma unroll
                for (int i = 0; i < 8; ++i) {
                    acc += (float)h0[i] * woA[i];
                    acc += (float)h1[i] * woA[8 + i];
                }
                acc += __shfl_xor(acc, 1, 64);
                acc += __shfl_xor(acc, 2, 64);
                acc += __shfl_xor(acc, 4, 64);
                if (l8 == 0) xs[1 + tt][mA * 2 + oA] = acc + boA;
            }
            __syncthreads();

            // pass B: residual MLP + violations + stores; thread = (tB, mB, qB)
            {
                const float xp0 = xs[tB][mB*2], xp1 = xs[tB][mB*2+1];
                const f32x2 vt2 = *(const f32x2*)&v_lds[(t0 + tB) * 8 + mB * 2];
                float rss0 = 0.0f, rss1 = 0.0f;
#pragma unroll
                for (int uu = 0; uu < 16; ++uu) {
                    const int u = qB * 16 + uu;
                    const f32x4 wA = *(const f32x4*)&wpk[u][0];
                    const f32x4 wB = *(const f32x4*)&wpk[u][4];
                    const float hu = fmaxf(wB[0] + wA[0]*xp0 + wA[1]*xp1 + wA[2]*vt2[0] + wA[3]*vt2[1], 0.0f);
                    rss0 += hu * wB[1];
                    rss1 += hu * wB[2];
                }
                rss0 += __shfl_xor(rss0, 1, 64);
                rss1 += __shfl_xor(rss1, 1, 64);
                rss0 += __shfl_xor(rss0, 2, 64);
                rss1 += __shfl_xor(rss1, 2, 64);
                if (qB < 2) {
                    const int o = qB;
                    const float xpred = xs[tB + 1][mB*2 + o];
                    const float xpv   = xs[tB][mB*2 + o];
                    const float vv    = v_lds[(t0 + tB) * 8 + mB*2 + o];
                    const float resid = (o ? rss1 : rss0) + b2B;
                    const float viol  = xpred - (xpv + vv + resid);
                    const size_t base = (size_t)(row0 + mB) * (SS * 2) + (t0 + tB) * 2 + o;
                    out[base] = xpred;
                    out[(size_t)BB * SS * 2 + base] = viol;
                }
                if (tid < 8) xc[(f + 1) & 1][tid] = xs[RS][tid];   // carry to next window
            }
            __syncthreads();
        }
    }
}

extern "C" void kernel_launch(void* const* d_in, const int* in_sizes, int n_in,
                              void* d_out, int out_size, void* d_ws, size_t ws_size,
                              hipStream_t stream) {
    pig_kernel<<<dim3(NBLK), dim3(BLK), 0, stream>>>(
        (const float*)d_in[0],  (const float*)d_in[1],  (const float*)d_in[2],
        (const float*)d_in[3],  (const float*)d_in[4],  (const float*)d_in[5],
        (const float*)d_in[6],  (const float*)d_in[7],  (const float*)d_in[8],
        (const float*)d_in[9],  (const float*)d_in[10], (const float*)d_in[11],
        (float*)d_out);
}